// Round 5
// baseline (225.075 us; speedup 1.0000x reference)
//
#include <hip/hip_runtime.h>
#include <cstdint>
#include <cstddef>

#define N_EMBD 1024
#define T_SEQ  2048
#define NBATCH 4
#define SPAN   256
#define C3     3072
// scale = sqrt(N_EMBD * SPAN) = 512

typedef float  floatx4 __attribute__((ext_vector_type(4)));
typedef __bf16 bf16x8  __attribute__((ext_vector_type(8)));

__device__ inline unsigned short f2bf(float f) {
    union { float f; unsigned u; } x; x.f = f;
    unsigned u = x.u;
    unsigned r = (u + 0x7fffu + ((u >> 16) & 1u)) >> 16;
    return (unsigned short)r;
}

typedef __attribute__((address_space(1))) const void GVOID;
typedef __attribute__((address_space(3))) void LVOID;
__device__ inline void gl2lds16(const void* g, void* l) {
    __builtin_amdgcn_global_load_lds((GVOID*)g, (LVOID*)l, 16, 0, 0);
}

// --- swizzled staging helpers -----------------------------------------------
// 128 rows x 32 cols bf16. LDS chunk slot c of row r holds global chunk c^((r>>1)&3).
// Reader chunk offset: qk = ((lane>>4) ^ ((lane>>1)&3)) * 8.
__device__ inline void stage128x32(const unsigned short* g, size_t stride,
                                   unsigned short* lds, int lane, int wave) {
    const int r     = wave * 16 + (lane >> 2);
    const int chunk = (lane & 3) ^ ((r >> 1) & 3);
    const unsigned short* src = g + (size_t)r * stride + chunk * 8;
    gl2lds16(src,               &lds[(wave * 16) * 32]);
    gl2lds16(src + 64 * stride, &lds[(64 + wave * 16) * 32]);
}

// 64 rows x 64 cols bf16, 256-thread WG. Slot c of row r holds global chunk c^(r&7).
__device__ inline void stage64x64(const unsigned short* g, size_t stride,
                                  unsigned short* lds, int lane, int wave) {
#pragma unroll
    for (int rnd = 0; rnd < 2; rnd++) {
        const int r = rnd * 32 + wave * 8 + (lane >> 3);
        const int chunk = (lane & 7) ^ (r & 7);
        gl2lds16(g + (size_t)r * stride + chunk * 8, &lds[(rnd * 32 + wave * 8) * 64]);
    }
}

// 32 rows x 64 cols bf16, 256-thread WG, 1 round.
__device__ inline void stage32x64(const unsigned short* g, size_t stride,
                                  unsigned short* lds, int lane, int wave) {
    const int r = wave * 8 + (lane >> 3);
    const int chunk = (lane & 7) ^ (r & 7);
    gl2lds16(g + (size_t)r * stride + chunk * 8, &lds[(wave * 8) * 64]);
}

// Swizzled fragment read: 16B of row `row`, k-substep ks (0/1), q = lane>>4.
__device__ inline bf16x8 frag_ld(const unsigned short* buf, int row, int ks, int q) {
    return *(const bf16x8*)&buf[row * 64 + (((ks * 4 + q) ^ (row & 7)) * 8)];
}

// ---------------------------------------------------------------------------
// K0: fused conversions. blocks [0,8192): x fp32->bf16. blocks [8192,11264): W -> WbT.
__global__ __launch_bounds__(256) void k_prep(const float* __restrict__ x,
                                              unsigned short* __restrict__ Xb,
                                              const float* __restrict__ W,
                                              unsigned short* __restrict__ WbT) {
    __shared__ unsigned short t[32][33];
    if (blockIdx.x < 8192) {
        int i = (blockIdx.x * 256 + threadIdx.x) * 4;
        float4 v = *(const float4*)(x + i);
        ushort4 o;
        o.x = f2bf(v.x); o.y = f2bf(v.y); o.z = f2bf(v.z); o.w = f2bf(v.w);
        *(ushort4*)(Xb + i) = o;
    } else {
        int bid = blockIdx.x - 8192;
        int k0 = (bid & 31) * 32, n0 = (bid >> 5) * 32;
        int tx = threadIdx.x & 31, ty = threadIdx.x >> 5;
#pragma unroll
        for (int i = 0; i < 4; i++) {
            int k = k0 + ty + i * 8;
            t[ty + i * 8][tx] = f2bf(W[(size_t)k * C3 + n0 + tx]);
        }
        __syncthreads();
#pragma unroll
        for (int i = 0; i < 4; i++) {
            int n = n0 + ty + i * 8;
            WbT[(size_t)n * N_EMBD + k0 + tx] = t[tx][ty + i * 8];
        }
    }
}

// ---------------------------------------------------------------------------
// K1: unified QKV GEMM, 128x128 tile, BK=32, 16 KB LDS, grid 24x64.
// EXACT r0 version (71.4 us, MfmaUtil 29.5, ~2.3-3 WGs/CU cross-WG overlap).
// r2/r3 post-mortem: 8-phase/fat-phase 256x128 ports at 1 WG/CU were
// LDS-read-bound and lost cross-WG TLP -> 87-97 us. Do NOT re-pipeline
// without per-wave 128x64 slabs.
__global__ __launch_bounds__(256) void k_gemm(const unsigned short* __restrict__ Xb,
                                              const unsigned short* __restrict__ WbT,
                                              const float* __restrict__ bqkv,
                                              unsigned short* __restrict__ QK,
                                              unsigned short* __restrict__ Vt) {
    __shared__ unsigned short As[4096];
    __shared__ unsigned short Bs[4096];
    const int tid = threadIdx.x, lane = tid & 63, wave = tid >> 6;
    const int bx = blockIdx.x, m0 = blockIdx.y * 128;
    const bool isV = (bx >= 16);
    const int n0 = isV ? (2048 + (bx - 16) * 128) : (bx * 128);
    const int wr = wave >> 1, wc = wave & 1;

    floatx4 acc[4][4] = {};

    const unsigned short* gA = (isV ? WbT + (size_t)n0 * N_EMBD : Xb  + (size_t)m0 * N_EMBD);
    const unsigned short* gB = (isV ? Xb  + (size_t)m0 * N_EMBD : WbT + (size_t)n0 * N_EMBD);
    const int qk = ((lane >> 4) ^ ((lane >> 1) & 3)) * 8;
    const int ra = wr * 64 + (lane & 15);
    const int rb = wc * 64 + (lane & 15);

    for (int k0 = 0; k0 < N_EMBD; k0 += 32) {
        stage128x32(gA + k0, N_EMBD, As, lane, wave);
        stage128x32(gB + k0, N_EMBD, Bs, lane, wave);
        __syncthreads();
        bf16x8 a[4], b[4];
#pragma unroll
        for (int mi = 0; mi < 4; mi++) a[mi] = *(const bf16x8*)&As[(ra + mi * 16) * 32 + qk];
#pragma unroll
        for (int ni = 0; ni < 4; ni++) b[ni] = *(const bf16x8*)&Bs[(rb + ni * 16) * 32 + qk];
#pragma unroll
        for (int mi = 0; mi < 4; mi++)
#pragma unroll
            for (int ni = 0; ni < 4; ni++)
                acc[mi][ni] = __builtin_amdgcn_mfma_f32_16x16x32_bf16(a[mi], b[ni], acc[mi][ni], 0, 0, 0);
        __syncthreads();
    }

    // Unified epilogue.
    const int cn = lane & 15, q = lane >> 4;
    unsigned short* base = isV ? Vt : QK;
    const int rowbase = isV ? (((m0 >> 11) << 10) + (n0 - 2048)) : m0;
    const int colbase = isV ? (m0 & 2047) : n0;
#pragma unroll
    for (int mi = 0; mi < 4; mi++) {
#pragma unroll
        for (int r = 0; r < 4; r++) {
            const int arow = wr * 64 + mi * 16 + q * 4 + r;
            unsigned short* dst = base + (size_t)(rowbase + arow) * 2048 + colbase;
#pragma unroll
            for (int ni = 0; ni < 4; ni++) {
                const int acol = wc * 64 + ni * 16 + cn;
                const float bias = bqkv[n0 + (isV ? arow : acol)];
                dst[acol] = f2bf(acc[mi][ni][r] + bias);
            }
        }
    }
}

// ---------------------------------------------------------------------------
// K2: FUSED attention tail: scores + SV + LayerNorm, one WG per (b, 32 Q-rows).
// Grid (64, 4) = 256 WGs = exactly 1/CU. 256 threads = 4 waves.
//
// Band: rows [r0, r0+31] need K/V token tiles jt in [a-4, a], a = r0>>6 = qh>>1
// (always 5 tiles, clamped at 0).
//
// S-phase (band-at-once): S[32 x 5*64] over full K=1024 in ONE pass.
//   Per k-step (64 chans): stage Q-tile(32x64) + 5 K-tiles(64x64) into dbuf
//   with T3-minimal order {issue next stage; compute cur; ONE barrier} so
//   HBM latency hides under MFMA. Wave w owns S n-tile w of every jt:
//   per ks: 2 a-reads + 5 b-reads -> 10 MFMA (read:MFMA = 0.7).
// Relayout: mask+scale+bf16 in-register, write to Ss LDS (chunk-swizzled) —
//   identical rounding to the old global S path.
// V-phase: wave w owns channels [w*256,(w+1)*256). V b-frags read DIRECT from
//   global Vt[c][t] (8 contiguous t elems = one 16B load) — no LDS staging,
//   no barriers. acc_o[2][16] = full 32x1024 out rows in registers.
//   jt ascending, ks inner = same accumulation order as old k_sv.
// LN fused: shfl over 16-lane col-groups + 4-wave LDS reduce, apply, write.
__global__ __launch_bounds__(256) void k_attn(const unsigned short* __restrict__ QK,
                                              const unsigned short* __restrict__ Vt,
                                              const float* __restrict__ lw,
                                              const float* __restrict__ lb,
                                              float* __restrict__ out) {
    const int qh = blockIdx.x, b = blockIdx.y;
    const int r0 = qh * 32;
    const int jt0 = (qh >> 1) - 4;

    __shared__ unsigned short Qd[2][32 * 64];      //  8 KB
    __shared__ unsigned short Kd[2][5 * 64 * 64];  // 80 KB
    __shared__ unsigned short Ss[5][32 * 64];      // 20 KB
    __shared__ float red[2][32][4];                //  1 KB

    const int tid = threadIdx.x, lane = tid & 63, wave = tid >> 6;
    const int n15 = lane & 15, q = lane >> 4;

    const unsigned short* gQ = QK + (size_t)(b * T_SEQ + r0) * 2048;

    floatx4 acc_s[2][5] = {};

    // ---- S-phase ----
    stage32x64(gQ, 2048, Qd[0], lane, wave);
#pragma unroll
    for (int jtl = 0; jtl < 5; ++jtl) {
        const int jt = jt0 + jtl;
        if (jt >= 0)
            stage64x64(QK + (size_t)(b * T_SEQ + jt * 64) * 2048 + 1024,
                       2048, Kd[0] + jtl * 4096, lane, wave);
    }
    __syncthreads();

#pragma unroll 1
    for (int kst = 0; kst < 16; ++kst) {
        const int cur = kst & 1;
        if (kst < 15) {
            const int kc = (kst + 1) * 64;
            stage32x64(gQ + kc, 2048, Qd[cur ^ 1], lane, wave);
#pragma unroll
            for (int jtl = 0; jtl < 5; ++jtl) {
                const int jt = jt0 + jtl;
                if (jt >= 0)
                    stage64x64(QK + (size_t)(b * T_SEQ + jt * 64) * 2048 + 1024 + kc,
                               2048, Kd[cur ^ 1] + jtl * 4096, lane, wave);
            }
        }
#pragma unroll
        for (int ks = 0; ks < 2; ++ks) {
            bf16x8 a0 = frag_ld(Qd[cur], n15, ks, q);
            bf16x8 a1 = frag_ld(Qd[cur], 16 + n15, ks, q);
#pragma unroll
            for (int jtl = 0; jtl < 5; ++jtl) {
                if (jt0 + jtl < 0) continue;
                bf16x8 bk = frag_ld(Kd[cur] + jtl * 4096, wave * 16 + n15, ks, q);
                acc_s[0][jtl] = __builtin_amdgcn_mfma_f32_16x16x32_bf16(a0, bk, acc_s[0][jtl], 0, 0, 0);
                acc_s[1][jtl] = __builtin_amdgcn_mfma_f32_16x16x32_bf16(a1, bk, acc_s[1][jtl], 0, 0, 0);
            }
        }
        __syncthreads();
    }

    // ---- relayout: acc_s -> Ss (masked, scaled, bf16) ----
    {
        const int jl = wave * 16 + n15;
#pragma unroll
        for (int jtl = 0; jtl < 5; ++jtl) {
            const int jt = jt0 + jtl;
            if (jt < 0) continue;
            const int gj = jt * 64 + jl;
#pragma unroll
            for (int mi = 0; mi < 2; ++mi)
#pragma unroll
                for (int r = 0; r < 4; ++r) {
                    const int il = mi * 16 + q * 4 + r;
                    const int gi = r0 + il;
                    const float v = ((gj <= gi) && (gj > gi - SPAN))
                                        ? acc_s[mi][jtl][r] * (1.0f / 512.0f) : 0.0f;
                    Ss[jtl][il * 64 + (((jl >> 3) ^ (il & 7)) * 8) + (jl & 7)] = f2bf(v);
                }
        }
    }
    __syncthreads();

    // ---- V-phase: acc_o[mi][nt] += Ss . V, V direct from global ----
    floatx4 acc_o[2][16] = {};
    const unsigned short* gV = Vt + (size_t)(b * 1024 + wave * 256) * 2048;
#pragma unroll
    for (int jtl = 0; jtl < 5; ++jtl) {
        const int jt = jt0 + jtl;
        if (jt < 0) continue;
#pragma unroll
        for (int ks = 0; ks < 2; ++ks) {
            bf16x8 a0 = frag_ld(Ss[jtl], n15, ks, q);
            bf16x8 a1 = frag_ld(Ss[jtl], 16 + n15, ks, q);
            const size_t tb = (size_t)jt * 64 + ks * 32 + q * 8;
#pragma unroll
            for (int nt = 0; nt < 16; ++nt) {
                const bf16x8 bv = *(const bf16x8*)(gV + (size_t)(nt * 16 + n15) * 2048 + tb);
                acc_o[0][nt] = __builtin_amdgcn_mfma_f32_16x16x32_bf16(a0, bv, acc_o[0][nt], 0, 0, 0);
                acc_o[1][nt] = __builtin_amdgcn_mfma_f32_16x16x32_bf16(a1, bv, acc_o[1][nt], 0, 0, 0);
            }
        }
    }

    // ---- fused LayerNorm ----
#pragma unroll
    for (int mi = 0; mi < 2; ++mi)
#pragma unroll
        for (int r = 0; r < 4; ++r) {
            float s = 0.0f, sq = 0.0f;
#pragma unroll
            for (int nt = 0; nt < 16; ++nt) {
                const float v = acc_o[mi][nt][r];
                s += v; sq += v * v;
            }
#pragma unroll
            for (int off = 1; off < 16; off <<= 1) {
                s  += __shfl_xor(s, off, 64);
                sq += __shfl_xor(sq, off, 64);
            }
            if (n15 == 0) {
                red[0][mi * 16 + q * 4 + r][wave] = s;
                red[1][mi * 16 + q * 4 + r][wave] = sq;
            }
        }
    __syncthreads();

    float* po = out + (size_t)(b * T_SEQ + r0) * N_EMBD;
#pragma unroll
    for (int mi = 0; mi < 2; ++mi)
#pragma unroll
        for (int r = 0; r < 4; ++r) {
            const int row = mi * 16 + q * 4 + r;
            const float ts = red[0][row][0] + red[0][row][1] + red[0][row][2] + red[0][row][3];
            const float tq = red[1][row][0] + red[1][row][1] + red[1][row][2] + red[1][row][3];
            const float mean = ts * (1.0f / N_EMBD);
            const float var  = tq * (1.0f / N_EMBD) - mean * mean;
            const float rs = rsqrtf(var + 1e-5f);
#pragma unroll
            for (int nt = 0; nt < 16; ++nt) {
                const int c = wave * 256 + nt * 16 + n15;
                po[(size_t)row * N_EMBD + c] = (acc_o[mi][nt][r] - mean) * rs * lw[c] + lb[c];
            }
        }
}

// ---------------------------------------------------------------------------
extern "C" void kernel_launch(void* const* d_in, const int* in_sizes, int n_in,
                              void* d_out, int out_size, void* d_ws, size_t ws_size,
                              hipStream_t stream) {
    const float* x  = (const float*)d_in[0];
    const float* W  = (const float*)d_in[1];
    const float* bq = (const float*)d_in[2];
    const float* lw = (const float*)d_in[3];
    const float* lb = (const float*)d_in[4];
    float* out = (float*)d_out;
    char* ws = (char*)d_ws;

    // workspace layout (bytes):
    //  Xb   @ 0          16,777,216  (8192x1024 bf16) — dead after GEMM
    //  WbT  @ 16,777,216  6,291,456  (3072x1024 bf16)
    //  QK   @ 23,068,672 33,554,432  (8192x2048 bf16)
    //  Vt   @ 56,623,104 16,777,216  (4x1024x2048 bf16)
    //  total 73,400,320
    unsigned short* Xb   = (unsigned short*)(ws + 0);
    unsigned short* WbT  = (unsigned short*)(ws + 16777216);
    unsigned short* QK   = (unsigned short*)(ws + 23068672);
    unsigned short* Vt   = (unsigned short*)(ws + 56623104);

    k_prep <<<11264,        256, 0, stream>>>(x, Xb, W, WbT);
    k_gemm <<<dim3(24, 64), 256, 0, stream>>>(Xb, WbT, bq, QK, Vt);
    k_attn <<<dim3(64, 4),  256, 0, stream>>>(QK, Vt, lw, lb, out);
}

// Round 6
// 210.358 us; speedup vs baseline: 1.0700x; 1.0700x over previous
//
#include <hip/hip_runtime.h>
#include <cstdint>
#include <cstddef>

#define N_EMBD 1024
#define T_SEQ  2048
#define NBATCH 4
#define SPAN   256
#define C3     3072
// scale = sqrt(N_EMBD * SPAN) = 512

typedef float  floatx4 __attribute__((ext_vector_type(4)));
typedef __bf16 bf16x8  __attribute__((ext_vector_type(8)));

__device__ inline unsigned short f2bf(float f) {
    union { float f; unsigned u; } x; x.f = f;
    unsigned u = x.u;
    unsigned r = (u + 0x7fffu + ((u >> 16) & 1u)) >> 16;
    return (unsigned short)r;
}

typedef __attribute__((address_space(1))) const void GVOID;
typedef __attribute__((address_space(3))) void LVOID;
__device__ inline void gl2lds16(const void* g, void* l) {
    __builtin_amdgcn_global_load_lds((GVOID*)g, (LVOID*)l, 16, 0, 0);
}

// --- swizzled staging helpers -----------------------------------------------
// 128 rows x 32 cols bf16. LDS chunk slot c of row r holds global chunk c^((r>>1)&3).
// Reader chunk offset: qk = ((lane>>4) ^ ((lane>>1)&3)) * 8.
__device__ inline void stage128x32(const unsigned short* g, size_t stride,
                                   unsigned short* lds, int lane, int wave) {
    const int r     = wave * 16 + (lane >> 2);
    const int chunk = (lane & 3) ^ ((r >> 1) & 3);
    const unsigned short* src = g + (size_t)r * stride + chunk * 8;
    gl2lds16(src,               &lds[(wave * 16) * 32]);
    gl2lds16(src + 64 * stride, &lds[(64 + wave * 16) * 32]);
}

// 64 rows x 64 cols bf16, 256-thread WG. Slot c of row r holds global chunk c^(r&7).
__device__ inline void stage64x64(const unsigned short* g, size_t stride,
                                  unsigned short* lds, int lane, int wave) {
#pragma unroll
    for (int rnd = 0; rnd < 2; rnd++) {
        const int r = rnd * 32 + wave * 8 + (lane >> 3);
        const int chunk = (lane & 7) ^ (r & 7);
        gl2lds16(g + (size_t)r * stride + chunk * 8, &lds[(rnd * 32 + wave * 8) * 64]);
    }
}

// Swizzled fragment read: 16B of row `row`, k-substep ks (0/1), q = lane>>4.
__device__ inline bf16x8 frag_ld(const unsigned short* buf, int row, int ks, int q) {
    return *(const bf16x8*)&buf[row * 64 + (((ks * 4 + q) ^ (row & 7)) * 8)];
}

// ---------------------------------------------------------------------------
// K0: fused conversions. blocks [0,8192): x fp32->bf16. blocks [8192,11264): W -> WbT.
__global__ __launch_bounds__(256) void k_prep(const float* __restrict__ x,
                                              unsigned short* __restrict__ Xb,
                                              const float* __restrict__ W,
                                              unsigned short* __restrict__ WbT) {
    __shared__ unsigned short t[32][33];
    if (blockIdx.x < 8192) {
        int i = (blockIdx.x * 256 + threadIdx.x) * 4;
        float4 v = *(const float4*)(x + i);
        ushort4 o;
        o.x = f2bf(v.x); o.y = f2bf(v.y); o.z = f2bf(v.z); o.w = f2bf(v.w);
        *(ushort4*)(Xb + i) = o;
    } else {
        int bid = blockIdx.x - 8192;
        int k0 = (bid & 31) * 32, n0 = (bid >> 5) * 32;
        int tx = threadIdx.x & 31, ty = threadIdx.x >> 5;
#pragma unroll
        for (int i = 0; i < 4; i++) {
            int k = k0 + ty + i * 8;
            t[ty + i * 8][tx] = f2bf(W[(size_t)k * C3 + n0 + tx]);
        }
        __syncthreads();
#pragma unroll
        for (int i = 0; i < 4; i++) {
            int n = n0 + ty + i * 8;
            WbT[(size_t)n * N_EMBD + k0 + tx] = t[tx][ty + i * 8];
        }
    }
}

// ---------------------------------------------------------------------------
// K1: unified QKV GEMM, 128x128 tile, BK=32, 16 KB LDS, grid 24x64.
// EXACT r0 version (71.4 us, MfmaUtil 29.5, ~2.3-3 WGs/CU cross-WG overlap).
// r2/r3 post-mortem: 8-phase/fat-phase 256x128 ports at 1 WG/CU were
// LDS-read-bound and lost cross-WG TLP -> 87-97 us. Do NOT re-pipeline
// without per-wave 128x64 slabs. r5 post-mortem: 1 wave/SIMD fusion also
// loses; occupancy is the latency-hiding mechanism on this chip.
__global__ __launch_bounds__(256) void k_gemm(const unsigned short* __restrict__ Xb,
                                              const unsigned short* __restrict__ WbT,
                                              const float* __restrict__ bqkv,
                                              unsigned short* __restrict__ QK,
                                              unsigned short* __restrict__ Vt) {
    __shared__ unsigned short As[4096];
    __shared__ unsigned short Bs[4096];
    const int tid = threadIdx.x, lane = tid & 63, wave = tid >> 6;
    const int bx = blockIdx.x, m0 = blockIdx.y * 128;
    const bool isV = (bx >= 16);
    const int n0 = isV ? (2048 + (bx - 16) * 128) : (bx * 128);
    const int wr = wave >> 1, wc = wave & 1;

    floatx4 acc[4][4] = {};

    const unsigned short* gA = (isV ? WbT + (size_t)n0 * N_EMBD : Xb  + (size_t)m0 * N_EMBD);
    const unsigned short* gB = (isV ? Xb  + (size_t)m0 * N_EMBD : WbT + (size_t)n0 * N_EMBD);
    const int qk = ((lane >> 4) ^ ((lane >> 1) & 3)) * 8;
    const int ra = wr * 64 + (lane & 15);
    const int rb = wc * 64 + (lane & 15);

    for (int k0 = 0; k0 < N_EMBD; k0 += 32) {
        stage128x32(gA + k0, N_EMBD, As, lane, wave);
        stage128x32(gB + k0, N_EMBD, Bs, lane, wave);
        __syncthreads();
        bf16x8 a[4], b[4];
#pragma unroll
        for (int mi = 0; mi < 4; mi++) a[mi] = *(const bf16x8*)&As[(ra + mi * 16) * 32 + qk];
#pragma unroll
        for (int ni = 0; ni < 4; ni++) b[ni] = *(const bf16x8*)&Bs[(rb + ni * 16) * 32 + qk];
#pragma unroll
        for (int mi = 0; mi < 4; mi++)
#pragma unroll
            for (int ni = 0; ni < 4; ni++)
                acc[mi][ni] = __builtin_amdgcn_mfma_f32_16x16x32_bf16(a[mi], b[ni], acc[mi][ni], 0, 0, 0);
        __syncthreads();
    }

    // Unified epilogue.
    const int cn = lane & 15, q = lane >> 4;
    unsigned short* base = isV ? Vt : QK;
    const int rowbase = isV ? (((m0 >> 11) << 10) + (n0 - 2048)) : m0;
    const int colbase = isV ? (m0 & 2047) : n0;
#pragma unroll
    for (int mi = 0; mi < 4; mi++) {
#pragma unroll
        for (int r = 0; r < 4; r++) {
            const int arow = wr * 64 + mi * 16 + q * 4 + r;
            unsigned short* dst = base + (size_t)(rowbase + arow) * 2048 + colbase;
#pragma unroll
            for (int ni = 0; ni < 4; ni++) {
                const int acol = wc * 64 + ni * 16 + cn;
                const float bias = bqkv[n0 + (isV ? arow : acol)];
                dst[acol] = f2bf(acc[mi][ni][r] + bias);
            }
        }
    }
}

// ---------------------------------------------------------------------------
// K2: banded scores, 64x64 out tiles, BK=128 (2 k-steps per barrier-pair).
// 640 WGs 1D, XCD-chunked swizzle (chunk=80). Exact r4 version.
// S block layout: [(b*32+qb)*5+jj] -> 64x64 bf16 row-major.
__global__ __launch_bounds__(256) void k_scores(const unsigned short* __restrict__ QK,
                                                unsigned short* __restrict__ S) {
    const int logical = (blockIdx.x & 7) * 80 + (blockIdx.x >> 3);
    const int jj = logical % 5;
    const int qb = (logical / 5) & 31;
    const int b  = logical / 160;
    const int jb = qb - 4 + jj;
    if (jb < 0) return;

    __shared__ unsigned short Qs[2][4096];
    __shared__ unsigned short Ks[2][4096];
    const int tid = threadIdx.x, lane = tid & 63, wave = tid >> 6;
    const int wr = wave >> 1, wc = wave & 1;
    const int n15 = lane & 15, q = lane >> 4;

    floatx4 acc[2][2] = {};

    const unsigned short* gQ = QK + ((size_t)(b * T_SEQ + qb * 64)) * 2048;
    const unsigned short* gK = QK + ((size_t)(b * T_SEQ + jb * 64)) * 2048 + 1024;

    for (int k0 = 0; k0 < N_EMBD; k0 += 128) {
        stage64x64(gQ + k0,      2048, Qs[0], lane, wave);
        stage64x64(gQ + k0 + 64, 2048, Qs[1], lane, wave);
        stage64x64(gK + k0,      2048, Ks[0], lane, wave);
        stage64x64(gK + k0 + 64, 2048, Ks[1], lane, wave);
        __syncthreads();
#pragma unroll
        for (int h = 0; h < 2; h++) {
#pragma unroll
            for (int s = 0; s < 2; s++) {
                bf16x8 a[2], bbf[2];
#pragma unroll
                for (int mi = 0; mi < 2; mi++) {
                    const int row = wr * 32 + mi * 16 + n15;
                    a[mi] = *(const bf16x8*)&Qs[h][row * 64 + (((s * 4 + q) ^ (row & 7)) * 8)];
                }
#pragma unroll
                for (int ni = 0; ni < 2; ni++) {
                    const int row = wc * 32 + ni * 16 + n15;
                    bbf[ni] = *(const bf16x8*)&Ks[h][row * 64 + (((s * 4 + q) ^ (row & 7)) * 8)];
                }
#pragma unroll
                for (int mi = 0; mi < 2; mi++)
#pragma unroll
                    for (int ni = 0; ni < 2; ni++)
                        acc[mi][ni] = __builtin_amdgcn_mfma_f32_16x16x32_bf16(a[mi], bbf[ni], acc[mi][ni], 0, 0, 0);
            }
        }
        __syncthreads();
    }

    unsigned short* Sb = S + (((size_t)(b * 32 + qb) * 5 + jj) << 12);
#pragma unroll
    for (int mi = 0; mi < 2; mi++)
#pragma unroll
        for (int ni = 0; ni < 2; ni++)
#pragma unroll
            for (int r = 0; r < 4; r++) {
                const int il = wr * 32 + mi * 16 + q * 4 + r;
                const int jl = wc * 32 + ni * 16 + n15;
                const int gi = qb * 64 + il, gj = jb * 64 + jl;
                const float v = ((gj <= gi) && (gj > gi - SPAN)) ? acc[mi][ni][r] * (1.0f / 512.0f) : 0.0f;
                Sb[il * 64 + jl] = f2bf(v);
            }
}

// ---------------------------------------------------------------------------
// K3: FUSED SV + LayerNorm. One WG per (b, 32 Q-rows): grid (64,4) = 256 WGs
// = 1/CU, 512 threads = 8 waves = 2 waves/SIMD (r5 lesson: keep waves/SIMD
// >= 2). LDS only 22 KB.
//   Each WG owns rows [r0, r0+32) x ALL 1024 channels -> LN is WG-local.
//   Wave w owns channels [w*128, (w+1)*128): acc[2][8] = 64 VGPRs.
//   S: 5 half-tiles (32x64) of the qb=r0>>6 S-blocks, staged once (swizzled).
//   V: direct from global Vt[c][t] (16B contiguous b-frags, L2-resident 2MB
//      per-b slice). Zero barriers in the V loop -> deep load pipelining.
//   Accumulation order (jt asc, ks inner) == old k_sv -> bit-identical SV.
__global__ __launch_bounds__(512) void k_svln(const unsigned short* __restrict__ S,
                                              const unsigned short* __restrict__ Vt,
                                              const float* __restrict__ lw,
                                              const float* __restrict__ lb,
                                              float* __restrict__ out) {
    const int qh = blockIdx.x, b = blockIdx.y;
    const int r0 = qh * 32;
    const int qb = qh >> 1, half = qh & 1;
    const int jt0 = qb - 4;

    __shared__ unsigned short Ss[5][32 * 64];  // 20 KB
    __shared__ float red[2][32][8];            //  2 KB

    const int tid = threadIdx.x, lane = tid & 63, wave = tid >> 6;
    const int n15 = lane & 15, q = lane >> 4;

    // ---- stage the 5 S half-tiles (rows half*32..+32 of each 64x64 block) ----
    // 512 threads cover 64 rows/round -> 2 tiles per round, 3 rounds.
    const unsigned short* Sg = S + (((size_t)(b * 32 + qb) * 5) << 12) + half * 2048;
#pragma unroll
    for (int rnd = 0; rnd < 3; ++rnd) {
        const int tl = rnd * 2 + (wave >> 2);
        if (tl < 5 && (jt0 + tl) >= 0) {
            const int r = (wave & 3) * 8 + (lane >> 3);
            const int chunk = (lane & 7) ^ (r & 7);
            gl2lds16(Sg + ((size_t)tl << 12) + (size_t)r * 64 + chunk * 8,
                     &Ss[tl][((wave & 3) * 8) * 64]);
        }
    }
    __syncthreads();

    // ---- SV: acc[mi][nt] over K=320 band, V direct from global ----
    floatx4 acc[2][8] = {};
    const unsigned short* gV = Vt + (size_t)(b * 1024 + wave * 128) * 2048;
#pragma unroll
    for (int jtl = 0; jtl < 5; ++jtl) {
        const int jt = jt0 + jtl;
        if (jt < 0) continue;
#pragma unroll
        for (int ks = 0; ks < 2; ++ks) {
            bf16x8 a0 = frag_ld(Ss[jtl], n15, ks, q);
            bf16x8 a1 = frag_ld(Ss[jtl], 16 + n15, ks, q);
            const size_t tb = (size_t)jt * 64 + ks * 32 + q * 8;
#pragma unroll
            for (int nt = 0; nt < 8; ++nt) {
                const bf16x8 bv = *(const bf16x8*)(gV + (size_t)(nt * 16 + n15) * 2048 + tb);
                acc[0][nt] = __builtin_amdgcn_mfma_f32_16x16x32_bf16(a0, bv, acc[0][nt], 0, 0, 0);
                acc[1][nt] = __builtin_amdgcn_mfma_f32_16x16x32_bf16(a1, bv, acc[1][nt], 0, 0, 0);
            }
        }
    }

    // ---- fused LayerNorm: per-row stats across 8 waves ----
#pragma unroll
    for (int mi = 0; mi < 2; ++mi)
#pragma unroll
        for (int r = 0; r < 4; ++r) {
            float s = 0.0f, sq = 0.0f;
#pragma unroll
            for (int nt = 0; nt < 8; ++nt) {
                const float v = acc[mi][nt][r];
                s += v; sq += v * v;
            }
#pragma unroll
            for (int off = 1; off < 16; off <<= 1) {
                s  += __shfl_xor(s, off, 64);
                sq += __shfl_xor(sq, off, 64);
            }
            if (n15 == 0) {
                red[0][mi * 16 + q * 4 + r][wave] = s;
                red[1][mi * 16 + q * 4 + r][wave] = sq;
            }
        }
    __syncthreads();

    float* po = out + (size_t)(b * T_SEQ + r0) * N_EMBD;
#pragma unroll
    for (int mi = 0; mi < 2; ++mi)
#pragma unroll
        for (int r = 0; r < 4; ++r) {
            const int row = mi * 16 + q * 4 + r;
            float ts = 0.0f, tq = 0.0f;
#pragma unroll
            for (int w = 0; w < 8; ++w) { ts += red[0][row][w]; tq += red[1][row][w]; }
            const float mean = ts * (1.0f / N_EMBD);
            const float var  = tq * (1.0f / N_EMBD) - mean * mean;
            const float rs = rsqrtf(var + 1e-5f);
#pragma unroll
            for (int nt = 0; nt < 8; ++nt) {
                const int c = wave * 128 + nt * 16 + n15;
                po[(size_t)row * N_EMBD + c] = (acc[mi][nt][r] - mean) * rs * lw[c] + lb[c];
            }
        }
}

// ---------------------------------------------------------------------------
extern "C" void kernel_launch(void* const* d_in, const int* in_sizes, int n_in,
                              void* d_out, int out_size, void* d_ws, size_t ws_size,
                              hipStream_t stream) {
    const float* x  = (const float*)d_in[0];
    const float* W  = (const float*)d_in[1];
    const float* bq = (const float*)d_in[2];
    const float* lw = (const float*)d_in[3];
    const float* lb = (const float*)d_in[4];
    float* out = (float*)d_out;
    char* ws = (char*)d_ws;

    // workspace layout (bytes):
    //  Xb   @ 0          16,777,216  (8192x1024 bf16) — dead after GEMM
    //  Sbuf @ 0           5,242,880  (4*32*5 blocks of 64x64 bf16) — aliases Xb
    //  WbT  @ 16,777,216  6,291,456  (3072x1024 bf16)
    //  QK   @ 23,068,672 33,554,432  (8192x2048 bf16)
    //  Vt   @ 56,623,104 16,777,216  (4x1024x2048 bf16)
    //  total 73,400,320
    unsigned short* Xb   = (unsigned short*)(ws + 0);
    unsigned short* Sbuf = (unsigned short*)(ws + 0);
    unsigned short* WbT  = (unsigned short*)(ws + 16777216);
    unsigned short* QK   = (unsigned short*)(ws + 23068672);
    unsigned short* Vt   = (unsigned short*)(ws + 56623104);

    k_prep   <<<11264,        256, 0, stream>>>(x, Xb, W, WbT);
    k_gemm   <<<dim3(24, 64), 256, 0, stream>>>(Xb, WbT, bq, QK, Vt);
    k_scores <<<640,          256, 0, stream>>>(QK, Sbuf);
    k_svln   <<<dim3(64, 4),  512, 0, stream>>>(Sbuf, Vt, lw, lb, out);
}

// Round 7
// 203.230 us; speedup vs baseline: 1.1075x; 1.0351x over previous
//
#include <hip/hip_runtime.h>
#include <cstdint>
#include <cstddef>

#define N_EMBD 1024
#define T_SEQ  2048
#define NBATCH 4
#define SPAN   256
#define C3     3072
// scale = sqrt(N_EMBD * SPAN) = 512

typedef float  floatx4 __attribute__((ext_vector_type(4)));
typedef __bf16 bf16x8  __attribute__((ext_vector_type(8)));

__device__ inline unsigned short f2bf(float f) {
    union { float f; unsigned u; } x; x.f = f;
    unsigned u = x.u;
    unsigned r = (u + 0x7fffu + ((u >> 16) & 1u)) >> 16;
    return (unsigned short)r;
}

typedef __attribute__((address_space(1))) const void GVOID;
typedef __attribute__((address_space(3))) void LVOID;
__device__ inline void gl2lds16(const void* g, void* l) {
    __builtin_amdgcn_global_load_lds((GVOID*)g, (LVOID*)l, 16, 0, 0);
}

// --- swizzled staging helpers -----------------------------------------------
// 128 rows x 32 cols bf16. LDS chunk slot c of row r holds global chunk c^((r>>1)&3).
// Reader chunk offset: qk = ((lane>>4) ^ ((lane>>1)&3)) * 8.
__device__ inline void stage128x32(const unsigned short* g, size_t stride,
                                   unsigned short* lds, int lane, int wave) {
    const int r     = wave * 16 + (lane >> 2);
    const int chunk = (lane & 3) ^ ((r >> 1) & 3);
    const unsigned short* src = g + (size_t)r * stride + chunk * 8;
    gl2lds16(src,               &lds[(wave * 16) * 32]);
    gl2lds16(src + 64 * stride, &lds[(64 + wave * 16) * 32]);
}

// 64 rows x 64 cols bf16, 256-thread WG. Slot c of row r holds global chunk c^(r&7).
__device__ inline void stage64x64(const unsigned short* g, size_t stride,
                                  unsigned short* lds, int lane, int wave) {
#pragma unroll
    for (int rnd = 0; rnd < 2; rnd++) {
        const int r = rnd * 32 + wave * 8 + (lane >> 3);
        const int chunk = (lane & 7) ^ (r & 7);
        gl2lds16(g + (size_t)r * stride + chunk * 8, &lds[(rnd * 32 + wave * 8) * 64]);
    }
}

// 128 rows x 64 cols bf16. 4 rounds.
__device__ inline void stage128x64(const unsigned short* g, size_t stride,
                                   unsigned short* lds, int lane, int wave) {
#pragma unroll
    for (int rnd = 0; rnd < 4; rnd++) {
        const int r = rnd * 32 + wave * 8 + (lane >> 3);
        const int chunk = (lane & 7) ^ (r & 7);
        gl2lds16(g + (size_t)r * stride + chunk * 8, &lds[(rnd * 32 + wave * 8) * 64]);
    }
}

// Swizzled fragment read: 16B of row `row`, k-substep ks (0/1), q = lane>>4.
__device__ inline bf16x8 frag_ld(const unsigned short* buf, int row, int ks, int q) {
    return *(const bf16x8*)&buf[row * 64 + (((ks * 4 + q) ^ (row & 7)) * 8)];
}

// ---------------------------------------------------------------------------
// K0: fused conversions. blocks [0,8192): x fp32->bf16. blocks [8192,11264): W -> WbT.
__global__ __launch_bounds__(256) void k_prep(const float* __restrict__ x,
                                              unsigned short* __restrict__ Xb,
                                              const float* __restrict__ W,
                                              unsigned short* __restrict__ WbT) {
    __shared__ unsigned short t[32][33];
    if (blockIdx.x < 8192) {
        int i = (blockIdx.x * 256 + threadIdx.x) * 4;
        float4 v = *(const float4*)(x + i);
        ushort4 o;
        o.x = f2bf(v.x); o.y = f2bf(v.y); o.z = f2bf(v.z); o.w = f2bf(v.w);
        *(ushort4*)(Xb + i) = o;
    } else {
        int bid = blockIdx.x - 8192;
        int k0 = (bid & 31) * 32, n0 = (bid >> 5) * 32;
        int tx = threadIdx.x & 31, ty = threadIdx.x >> 5;
#pragma unroll
        for (int i = 0; i < 4; i++) {
            int k = k0 + ty + i * 8;
            t[ty + i * 8][tx] = f2bf(W[(size_t)k * C3 + n0 + tx]);
        }
        __syncthreads();
#pragma unroll
        for (int i = 0; i < 4; i++) {
            int n = n0 + ty + i * 8;
            WbT[(size_t)n * N_EMBD + k0 + tx] = t[tx][ty + i * 8];
        }
    }
}

// ---------------------------------------------------------------------------
// K1: unified QKV GEMM, 128x128 tile, BK=32, 16 KB LDS. EXACT r0 inner loop
// (71.4 us, MfmaUtil 29.5, ~3 WGs/CU). ONLY change vs r4: 1D grid 1536 with
// XCD-chunked swizzle — each XCD owns 8 contiguous m-panels (all 24 n-blocks),
// so the A-panel (256 KB) is fetched once per XCD L2 instead of 8x. Pure
// block remap, outputs bit-identical.
// r2/r3/r5/r6 post-mortem: do NOT restructure; occupancy >= 3 WGs/CU is the
// latency-hiding mechanism on this chip.
__global__ __launch_bounds__(256) void k_gemm(const unsigned short* __restrict__ Xb,
                                              const unsigned short* __restrict__ WbT,
                                              const float* __restrict__ bqkv,
                                              unsigned short* __restrict__ QK,
                                              unsigned short* __restrict__ Vt) {
    __shared__ unsigned short As[4096];
    __shared__ unsigned short Bs[4096];
    const int tid = threadIdx.x, lane = tid & 63, wave = tid >> 6;
    // XCD-chunked bijective swizzle: 1536 = 8 * 192
    const int logical = (blockIdx.x & 7) * 192 + (blockIdx.x >> 3);
    const int bx = logical % 24;
    const int m0 = (logical / 24) * 128;
    const bool isV = (bx >= 16);
    const int n0 = isV ? (2048 + (bx - 16) * 128) : (bx * 128);
    const int wr = wave >> 1, wc = wave & 1;

    floatx4 acc[4][4] = {};

    const unsigned short* gA = (isV ? WbT + (size_t)n0 * N_EMBD : Xb  + (size_t)m0 * N_EMBD);
    const unsigned short* gB = (isV ? Xb  + (size_t)m0 * N_EMBD : WbT + (size_t)n0 * N_EMBD);
    const int qk = ((lane >> 4) ^ ((lane >> 1) & 3)) * 8;
    const int ra = wr * 64 + (lane & 15);
    const int rb = wc * 64 + (lane & 15);

    for (int k0 = 0; k0 < N_EMBD; k0 += 32) {
        stage128x32(gA + k0, N_EMBD, As, lane, wave);
        stage128x32(gB + k0, N_EMBD, Bs, lane, wave);
        __syncthreads();
        bf16x8 a[4], b[4];
#pragma unroll
        for (int mi = 0; mi < 4; mi++) a[mi] = *(const bf16x8*)&As[(ra + mi * 16) * 32 + qk];
#pragma unroll
        for (int ni = 0; ni < 4; ni++) b[ni] = *(const bf16x8*)&Bs[(rb + ni * 16) * 32 + qk];
#pragma unroll
        for (int mi = 0; mi < 4; mi++)
#pragma unroll
            for (int ni = 0; ni < 4; ni++)
                acc[mi][ni] = __builtin_amdgcn_mfma_f32_16x16x32_bf16(a[mi], b[ni], acc[mi][ni], 0, 0, 0);
        __syncthreads();
    }

    // Unified epilogue.
    const int cn = lane & 15, q = lane >> 4;
    unsigned short* base = isV ? Vt : QK;
    const int rowbase = isV ? (((m0 >> 11) << 10) + (n0 - 2048)) : m0;
    const int colbase = isV ? (m0 & 2047) : n0;
#pragma unroll
    for (int mi = 0; mi < 4; mi++) {
#pragma unroll
        for (int r = 0; r < 4; r++) {
            const int arow = wr * 64 + mi * 16 + q * 4 + r;
            unsigned short* dst = base + (size_t)(rowbase + arow) * 2048 + colbase;
#pragma unroll
            for (int ni = 0; ni < 4; ni++) {
                const int acol = wc * 64 + ni * 16 + cn;
                const float bias = bqkv[n0 + (isV ? arow : acol)];
                dst[acol] = f2bf(acc[mi][ni][r] + bias);
            }
        }
    }
}

// ---------------------------------------------------------------------------
// K2: banded scores, jj-PAIRED: one WG computes a 64x128 out (two adjacent jj
// blocks), BK=128. 4 waves as 2M x 2N -> per-wave 32x64 slab: 6 ds_read per
// 8 MFMA (ratio 0.75 vs r4's 1.0), Q staged once per 2 jj. 384 WGs
// (=3 pairs x 32 qb x 4 b), XCD-chunked swizzle (chunk=48) keeps the 3
// pair-WGs of one qb on one XCD. LDS 48 KB -> 3 WGs/CU (r4 occupancy kept).
// Accumulation order (k0 asc, h asc, s asc) identical to r4 -> bit-identical S.
// S block layout unchanged: [(b*32+qb)*5+jj] -> 64x64 bf16 row-major.
__global__ __launch_bounds__(256) void k_scores(const unsigned short* __restrict__ QK,
                                                unsigned short* __restrict__ S) {
    const int logical = (blockIdx.x & 7) * 48 + (blockIdx.x >> 3);
    const int p  = logical % 3;
    const int qb = (logical / 3) & 31;
    const int b  = logical / 96;
    const int jj0 = 2 * p;
    const int jb0 = qb - 4 + jj0;
    const bool v0 = (jb0 >= 0);                 // jj0 in {0,2,4}, always < 5
    const bool v1 = (p < 2) && (jb0 + 1 >= 0);  // jj1 = jj0+1 exists and in-band
    if (!v0 && !v1) return;

    __shared__ unsigned short Qs[2][4096];      // 16 KB (two 64-chan halves)
    __shared__ unsigned short Ks[2][2][4096];   // 32 KB ([half][jj-of-pair])
    const int tid = threadIdx.x, lane = tid & 63, wave = tid >> 6;
    const int wr = wave >> 1, wc = wave & 1;    // wc selects jj block of pair
    const int n15 = lane & 15, q = lane >> 4;
    const bool myv = wc ? v1 : v0;

    floatx4 acc[2][4] = {};

    const unsigned short* gQ  = QK + ((size_t)(b * T_SEQ + qb * 64)) * 2048;
    const unsigned short* gK0 = QK + ((size_t)(b * T_SEQ + jb0 * 64)) * 2048 + 1024;
    const unsigned short* gK1 = gK0 + (size_t)64 * 2048;

    for (int k0 = 0; k0 < N_EMBD; k0 += 128) {
        stage64x64(gQ + k0,      2048, Qs[0], lane, wave);
        stage64x64(gQ + k0 + 64, 2048, Qs[1], lane, wave);
        if (v0) {
            stage64x64(gK0 + k0,      2048, Ks[0][0], lane, wave);
            stage64x64(gK0 + k0 + 64, 2048, Ks[1][0], lane, wave);
        }
        if (v1) {
            stage64x64(gK1 + k0,      2048, Ks[0][1], lane, wave);
            stage64x64(gK1 + k0 + 64, 2048, Ks[1][1], lane, wave);
        }
        __syncthreads();
        if (myv) {
#pragma unroll
            for (int h = 0; h < 2; h++) {
#pragma unroll
                for (int s = 0; s < 2; s++) {
                    bf16x8 a[2], bbf[4];
#pragma unroll
                    for (int mi = 0; mi < 2; mi++)
                        a[mi] = frag_ld(Qs[h], wr * 32 + mi * 16 + n15, s, q);
#pragma unroll
                    for (int ni = 0; ni < 4; ni++)
                        bbf[ni] = frag_ld(Ks[h][wc], ni * 16 + n15, s, q);
#pragma unroll
                    for (int mi = 0; mi < 2; mi++)
#pragma unroll
                        for (int ni = 0; ni < 4; ni++)
                            acc[mi][ni] = __builtin_amdgcn_mfma_f32_16x16x32_bf16(a[mi], bbf[ni], acc[mi][ni], 0, 0, 0);
                }
            }
        }
        __syncthreads();
    }

    if (!myv) return;
    const int jb = jb0 + wc, jj = jj0 + wc;
    unsigned short* Sb = S + (((size_t)(b * 32 + qb) * 5 + jj) << 12);
#pragma unroll
    for (int mi = 0; mi < 2; mi++)
#pragma unroll
        for (int ni = 0; ni < 4; ni++)
#pragma unroll
            for (int r = 0; r < 4; r++) {
                const int il = wr * 32 + mi * 16 + q * 4 + r;
                const int jl = ni * 16 + n15;
                const int gi = qb * 64 + il, gj = jb * 64 + jl;
                const float v = ((gj <= gi) && (gj > gi - SPAN)) ? acc[mi][ni][r] * (1.0f / 512.0f) : 0.0f;
                Sb[il * 64 + jl] = f2bf(v);
            }
}

// ---------------------------------------------------------------------------
// K3: out[64 x 128] = sum_jj S(64x64) @ V(64x128). 1024 WGs 1D, XCD-chunked
// swizzle (chunk=128). jj-tiles processed in pairs per barrier-pair.
// EXACT r4 version (part of the 195.8 us best).
__global__ __launch_bounds__(256) void k_sv(const unsigned short* __restrict__ S,
                                            const unsigned short* __restrict__ Vt,
                                            float* __restrict__ out) {
    const int logical = (blockIdx.x & 7) * 128 + (blockIdx.x >> 3);
    const int cg = logical & 7;
    const int qb = (logical >> 3) & 31;
    const int b  = logical >> 8;
    const int c0 = cg * 128;

    __shared__ unsigned short Ss[2][4096];
    __shared__ unsigned short Vs[2][8192];
    const int tid = threadIdx.x, lane = tid & 63, wave = tid >> 6;
    const int wr = wave >> 1, wc = wave & 1;
    const int n15 = lane & 15, q = lane >> 4;

    floatx4 acc[2][4] = {};

    const size_t vbase = ((size_t)(b * 1024 + c0)) * 2048;
    const size_t sbase = ((size_t)(b * 32 + qb) * 5) << 12;

    for (int j0 = 0; j0 < 5; j0 += 2) {
        const int nv = (j0 < 4) ? 2 : 1;
        bool val[2] = {false, false};
#pragma unroll
        for (int t = 0; t < 2; t++) {
            if (t < nv && (qb - 4 + j0 + t) >= 0) {
                val[t] = true;
                stage64x64 (S + sbase + ((size_t)(j0 + t) << 12), 64, Ss[t], lane, wave);
                stage128x64(Vt + vbase + (size_t)(qb - 4 + j0 + t) * 64, 2048, Vs[t], lane, wave);
            }
        }
        __syncthreads();
#pragma unroll
        for (int t = 0; t < 2; t++) {
            if (!val[t]) continue;
#pragma unroll
            for (int s = 0; s < 2; s++) {
                bf16x8 a[2], bbf[4];
#pragma unroll
                for (int mi = 0; mi < 2; mi++) {
                    const int row = wr * 32 + mi * 16 + n15;
                    a[mi] = *(const bf16x8*)&Ss[t][row * 64 + (((s * 4 + q) ^ (row & 7)) * 8)];
                }
#pragma unroll
                for (int ni = 0; ni < 4; ni++) {
                    const int row = wc * 64 + ni * 16 + n15;
                    bbf[ni] = *(const bf16x8*)&Vs[t][row * 64 + (((s * 4 + q) ^ (row & 7)) * 8)];
                }
#pragma unroll
                for (int mi = 0; mi < 2; mi++)
#pragma unroll
                    for (int ni = 0; ni < 4; ni++)
                        acc[mi][ni] = __builtin_amdgcn_mfma_f32_16x16x32_bf16(a[mi], bbf[ni], acc[mi][ni], 0, 0, 0);
            }
        }
        __syncthreads();
    }

#pragma unroll
    for (int mi = 0; mi < 2; mi++)
#pragma unroll
        for (int ni = 0; ni < 4; ni++)
#pragma unroll
            for (int r = 0; r < 4; r++) {
                const int il = wr * 32 + mi * 16 + q * 4 + r;
                const int cl = wc * 64 + ni * 16 + n15;
                out[((size_t)(b * T_SEQ + qb * 64 + il)) * N_EMBD + c0 + cl] = acc[mi][ni][r];
            }
}

// ---------------------------------------------------------------------------
// K4: in-place LayerNorm over last dim (1024), one WG per row
__global__ __launch_bounds__(256) void k_ln(float* __restrict__ out,
                                            const float* __restrict__ w,
                                            const float* __restrict__ bias) {
    __shared__ float red[8];
    const int t = threadIdx.x;
    float* p = out + (size_t)blockIdx.x * N_EMBD;
    float4 v = ((const float4*)p)[t];
    float s  = v.x + v.y + v.z + v.w;
    float sq = v.x * v.x + v.y * v.y + v.z * v.z + v.w * v.w;
#pragma unroll
    for (int off = 32; off; off >>= 1) {
        s  += __shfl_down(s, off, 64);
        sq += __shfl_down(sq, off, 64);
    }
    const int wave = t >> 6, lane = t & 63;
    if (lane == 0) { red[wave] = s; red[4 + wave] = sq; }
    __syncthreads();
    const float ts = red[0] + red[1] + red[2] + red[3];
    const float tq = red[4] + red[5] + red[6] + red[7];
    const float mean = ts * (1.0f / N_EMBD);
    const float var  = tq * (1.0f / N_EMBD) - mean * mean;
    const float rs = rsqrtf(var + 1e-5f);
    float4 wv = ((const float4*)w)[t];
    float4 bv = ((const float4*)bias)[t];
    float4 o;
    o.x = (v.x - mean) * rs * wv.x + bv.x;
    o.y = (v.y - mean) * rs * wv.y + bv.y;
    o.z = (v.z - mean) * rs * wv.z + bv.z;
    o.w = (v.w - mean) * rs * wv.w + bv.w;
    ((float4*)p)[t] = o;
}

// ---------------------------------------------------------------------------
extern "C" void kernel_launch(void* const* d_in, const int* in_sizes, int n_in,
                              void* d_out, int out_size, void* d_ws, size_t ws_size,
                              hipStream_t stream) {
    const float* x  = (const float*)d_in[0];
    const float* W  = (const float*)d_in[1];
    const float* bq = (const float*)d_in[2];
    const float* lw = (const float*)d_in[3];
    const float* lb = (const float*)d_in[4];
    float* out = (float*)d_out;
    char* ws = (char*)d_ws;

    // workspace layout (bytes):
    //  Xb   @ 0          16,777,216  (8192x1024 bf16) — dead after GEMM
    //  Sbuf @ 0           5,242,880  (4*32*5 blocks of 64x64 bf16) — aliases Xb
    //  WbT  @ 16,777,216  6,291,456  (3072x1024 bf16)
    //  QK   @ 23,068,672 33,554,432  (8192x2048 bf16)
    //  Vt   @ 56,623,104 16,777,216  (4x1024x2048 bf16)
    //  total 73,400,320
    unsigned short* Xb   = (unsigned short*)(ws + 0);
    unsigned short* Sbuf = (unsigned short*)(ws + 0);
    unsigned short* WbT  = (unsigned short*)(ws + 16777216);
    unsigned short* QK   = (unsigned short*)(ws + 23068672);
    unsigned short* Vt   = (unsigned short*)(ws + 56623104);

    k_prep   <<<11264, 256, 0, stream>>>(x, Xb, W, WbT);
    k_gemm   <<<1536,  256, 0, stream>>>(Xb, WbT, bq, QK, Vt);
    k_scores <<<384,   256, 0, stream>>>(QK, Sbuf);
    k_sv     <<<1024,  256, 0, stream>>>(Sbuf, Vt, out);
    k_ln     <<<8192,  256, 0, stream>>>(out, lw, lb);
}

// Round 8
// 199.530 us; speedup vs baseline: 1.1280x; 1.0185x over previous
//
#include <hip/hip_runtime.h>
#include <cstdint>
#include <cstddef>

#define N_EMBD 1024
#define T_SEQ  2048
#define NBATCH 4
#define SPAN   256
#define C3     3072
// scale = sqrt(N_EMBD * SPAN) = 512

typedef float  floatx4 __attribute__((ext_vector_type(4)));
typedef __bf16 bf16x8  __attribute__((ext_vector_type(8)));

__device__ inline unsigned short f2bf(float f) {
    union { float f; unsigned u; } x; x.f = f;
    unsigned u = x.u;
    unsigned r = (u + 0x7fffu + ((u >> 16) & 1u)) >> 16;
    return (unsigned short)r;
}

typedef __attribute__((address_space(1))) const void GVOID;
typedef __attribute__((address_space(3))) void LVOID;
__device__ inline void gl2lds16(const void* g, void* l) {
    __builtin_amdgcn_global_load_lds((GVOID*)g, (LVOID*)l, 16, 0, 0);
}

// --- swizzled staging helpers -----------------------------------------------
// 64-col layouts: LDS chunk slot c of row r holds global chunk c^(r&7);
// readers XOR the chunk index with (row&7) (frag_ld below).

// 64 rows x 64 cols bf16, 256-thread WG. 2 rounds, 2 loads/thread.
__device__ inline void stage64x64(const unsigned short* g, size_t stride,
                                  unsigned short* lds, int lane, int wave) {
#pragma unroll
    for (int rnd = 0; rnd < 2; rnd++) {
        const int r = rnd * 32 + wave * 8 + (lane >> 3);
        const int chunk = (lane & 7) ^ (r & 7);
        gl2lds16(g + (size_t)r * stride + chunk * 8, &lds[(rnd * 32 + wave * 8) * 64]);
    }
}

// 128 rows x 64 cols bf16, 256-thread WG. 4 rounds, 4 loads/thread.
__device__ inline void stage128x64(const unsigned short* g, size_t stride,
                                   unsigned short* lds, int lane, int wave) {
#pragma unroll
    for (int rnd = 0; rnd < 4; rnd++) {
        const int r = rnd * 32 + wave * 8 + (lane >> 3);
        const int chunk = (lane & 7) ^ (r & 7);
        gl2lds16(g + (size_t)r * stride + chunk * 8, &lds[(rnd * 32 + wave * 8) * 64]);
    }
}

// Swizzled fragment read: 16B of row `row`, k-substep ks (0/1), q = lane>>4.
__device__ inline bf16x8 frag_ld(const unsigned short* buf, int row, int ks, int q) {
    return *(const bf16x8*)&buf[row * 64 + (((ks * 4 + q) ^ (row & 7)) * 8)];
}

// ---------------------------------------------------------------------------
// K0: fused conversions. blocks [0,8192): x fp32->bf16. blocks [8192,11264): W -> WbT.
__global__ __launch_bounds__(256) void k_prep(const float* __restrict__ x,
                                              unsigned short* __restrict__ Xb,
                                              const float* __restrict__ W,
                                              unsigned short* __restrict__ WbT) {
    __shared__ unsigned short t[32][33];
    if (blockIdx.x < 8192) {
        int i = (blockIdx.x * 256 + threadIdx.x) * 4;
        float4 v = *(const float4*)(x + i);
        ushort4 o;
        o.x = f2bf(v.x); o.y = f2bf(v.y); o.z = f2bf(v.z); o.w = f2bf(v.w);
        *(ushort4*)(Xb + i) = o;
    } else {
        int bid = blockIdx.x - 8192;
        int k0 = (bid & 31) * 32, n0 = (bid >> 5) * 32;
        int tx = threadIdx.x & 31, ty = threadIdx.x >> 5;
#pragma unroll
        for (int i = 0; i < 4; i++) {
            int k = k0 + ty + i * 8;
            t[ty + i * 8][tx] = f2bf(W[(size_t)k * C3 + n0 + tx]);
        }
        __syncthreads();
#pragma unroll
        for (int i = 0; i < 4; i++) {
            int n = n0 + ty + i * 8;
            WbT[(size_t)n * N_EMBD + k0 + tx] = t[tx][ty + i * 8];
        }
    }
}

// ---------------------------------------------------------------------------
// K1: unified QKV GEMM, 128x128 tile, BK=64 (m97-proven config: 32 KB LDS,
// 32 MFMA per barrier-pair vs 16 at BK=32). Same 4-wave structure, same
// accumulation order (k0 asc by 32: ks inner) -> bit-identical outputs.
// XCD-chunked swizzle kept from r7 (FETCH 71.75->57.5 MB, time-neutral).
// r7 A/B: gemm is NOT HBM-bound (19% peak BW) — the lever is barrier count.
// r2/r3/r5/r6: do NOT restructure below ~2.5 WGs/CU; occupancy is the
// latency-hiding mechanism on this chip.
__global__ __launch_bounds__(256) void k_gemm(const unsigned short* __restrict__ Xb,
                                              const unsigned short* __restrict__ WbT,
                                              const float* __restrict__ bqkv,
                                              unsigned short* __restrict__ QK,
                                              unsigned short* __restrict__ Vt) {
    __shared__ unsigned short As[8192];   // 128 x 64 bf16, 16 KB
    __shared__ unsigned short Bs[8192];   // 128 x 64 bf16, 16 KB
    const int tid = threadIdx.x, lane = tid & 63, wave = tid >> 6;
    // XCD-chunked bijective swizzle: 1536 = 8 * 192
    const int logical = (blockIdx.x & 7) * 192 + (blockIdx.x >> 3);
    const int bx = logical % 24;
    const int m0 = (logical / 24) * 128;
    const bool isV = (bx >= 16);
    const int n0 = isV ? (2048 + (bx - 16) * 128) : (bx * 128);
    const int wr = wave >> 1, wc = wave & 1;

    floatx4 acc[4][4] = {};

    const unsigned short* gA = (isV ? WbT + (size_t)n0 * N_EMBD : Xb  + (size_t)m0 * N_EMBD);
    const unsigned short* gB = (isV ? Xb  + (size_t)m0 * N_EMBD : WbT + (size_t)n0 * N_EMBD);
    const int n15 = lane & 15, q = lane >> 4;
    const int ra = wr * 64 + n15;
    const int rb = wc * 64 + n15;

    for (int k0 = 0; k0 < N_EMBD; k0 += 64) {
        stage128x64(gA + k0, N_EMBD, As, lane, wave);
        stage128x64(gB + k0, N_EMBD, Bs, lane, wave);
        __syncthreads();
#pragma unroll
        for (int ks = 0; ks < 2; ks++) {
            bf16x8 a[4], b[4];
#pragma unroll
            for (int mi = 0; mi < 4; mi++) a[mi] = frag_ld(As, ra + mi * 16, ks, q);
#pragma unroll
            for (int ni = 0; ni < 4; ni++) b[ni] = frag_ld(Bs, rb + ni * 16, ks, q);
#pragma unroll
            for (int mi = 0; mi < 4; mi++)
#pragma unroll
                for (int ni = 0; ni < 4; ni++)
                    acc[mi][ni] = __builtin_amdgcn_mfma_f32_16x16x32_bf16(a[mi], b[ni], acc[mi][ni], 0, 0, 0);
        }
        __syncthreads();
    }

    // Unified epilogue.
    unsigned short* base = isV ? Vt : QK;
    const int rowbase = isV ? (((m0 >> 11) << 10) + (n0 - 2048)) : m0;
    const int colbase = isV ? (m0 & 2047) : n0;
#pragma unroll
    for (int mi = 0; mi < 4; mi++) {
#pragma unroll
        for (int r = 0; r < 4; r++) {
            const int arow = wr * 64 + mi * 16 + q * 4 + r;
            unsigned short* dst = base + (size_t)(rowbase + arow) * 2048 + colbase;
#pragma unroll
            for (int ni = 0; ni < 4; ni++) {
                const int acol = wc * 64 + ni * 16 + n15;
                const float bias = bqkv[n0 + (isV ? arow : acol)];
                dst[acol] = f2bf(acc[mi][ni][r] + bias);
            }
        }
    }
}

// ---------------------------------------------------------------------------
// K2: banded scores, 64x64 out tiles, BK=128 (2 k-steps per barrier-pair).
// 640 WGs 1D, XCD-chunked swizzle (chunk=80). EXACT r4 version (195.8 us best).
// r7 lesson: jj-pairing at 384 WGs = 1.5 WGs/CU grid-quantization loss. Keep 640.
// S block layout: [(b*32+qb)*5+jj] -> 64x64 bf16 row-major.
__global__ __launch_bounds__(256) void k_scores(const unsigned short* __restrict__ QK,
                                                unsigned short* __restrict__ S) {
    const int logical = (blockIdx.x & 7) * 80 + (blockIdx.x >> 3);
    const int jj = logical % 5;
    const int qb = (logical / 5) & 31;
    const int b  = logical / 160;
    const int jb = qb - 4 + jj;
    if (jb < 0) return;

    __shared__ unsigned short Qs[2][4096];
    __shared__ unsigned short Ks[2][4096];
    const int tid = threadIdx.x, lane = tid & 63, wave = tid >> 6;
    const int wr = wave >> 1, wc = wave & 1;
    const int n15 = lane & 15, q = lane >> 4;

    floatx4 acc[2][2] = {};

    const unsigned short* gQ = QK + ((size_t)(b * T_SEQ + qb * 64)) * 2048;
    const unsigned short* gK = QK + ((size_t)(b * T_SEQ + jb * 64)) * 2048 + 1024;

    for (int k0 = 0; k0 < N_EMBD; k0 += 128) {
        stage64x64(gQ + k0,      2048, Qs[0], lane, wave);
        stage64x64(gQ + k0 + 64, 2048, Qs[1], lane, wave);
        stage64x64(gK + k0,      2048, Ks[0], lane, wave);
        stage64x64(gK + k0 + 64, 2048, Ks[1], lane, wave);
        __syncthreads();
#pragma unroll
        for (int h = 0; h < 2; h++) {
#pragma unroll
            for (int s = 0; s < 2; s++) {
                bf16x8 a[2], bbf[2];
#pragma unroll
                for (int mi = 0; mi < 2; mi++) {
                    const int row = wr * 32 + mi * 16 + n15;
                    a[mi] = *(const bf16x8*)&Qs[h][row * 64 + (((s * 4 + q) ^ (row & 7)) * 8)];
                }
#pragma unroll
                for (int ni = 0; ni < 2; ni++) {
                    const int row = wc * 32 + ni * 16 + n15;
                    bbf[ni] = *(const bf16x8*)&Ks[h][row * 64 + (((s * 4 + q) ^ (row & 7)) * 8)];
                }
#pragma unroll
                for (int mi = 0; mi < 2; mi++)
#pragma unroll
                    for (int ni = 0; ni < 2; ni++)
                        acc[mi][ni] = __builtin_amdgcn_mfma_f32_16x16x32_bf16(a[mi], bbf[ni], acc[mi][ni], 0, 0, 0);
            }
        }
        __syncthreads();
    }

    unsigned short* Sb = S + (((size_t)(b * 32 + qb) * 5 + jj) << 12);
#pragma unroll
    for (int mi = 0; mi < 2; mi++)
#pragma unroll
        for (int ni = 0; ni < 2; ni++)
#pragma unroll
            for (int r = 0; r < 4; r++) {
                const int il = wr * 32 + mi * 16 + q * 4 + r;
                const int jl = wc * 32 + ni * 16 + n15;
                const int gi = qb * 64 + il, gj = jb * 64 + jl;
                const float v = ((gj <= gi) && (gj > gi - SPAN)) ? acc[mi][ni][r] * (1.0f / 512.0f) : 0.0f;
                Sb[il * 64 + jl] = f2bf(v);
            }
}

// ---------------------------------------------------------------------------
// K3: out[64 x 128] = sum_jj S(64x64) @ V(64x128). 1024 WGs 1D, XCD-chunked
// swizzle (chunk=128). jj-tiles processed in pairs per barrier-pair.
// EXACT r4 version (part of the 195.8 us best).
__global__ __launch_bounds__(256) void k_sv(const unsigned short* __restrict__ S,
                                            const unsigned short* __restrict__ Vt,
                                            float* __restrict__ out) {
    const int logical = (blockIdx.x & 7) * 128 + (blockIdx.x >> 3);
    const int cg = logical & 7;
    const int qb = (logical >> 3) & 31;
    const int b  = logical >> 8;
    const int c0 = cg * 128;

    __shared__ unsigned short Ss[2][4096];
    __shared__ unsigned short Vs[2][8192];
    const int tid = threadIdx.x, lane = tid & 63, wave = tid >> 6;
    const int wr = wave >> 1, wc = wave & 1;
    const int n15 = lane & 15, q = lane >> 4;

    floatx4 acc[2][4] = {};

    const size_t vbase = ((size_t)(b * 1024 + c0)) * 2048;
    const size_t sbase = ((size_t)(b * 32 + qb) * 5) << 12;

    for (int j0 = 0; j0 < 5; j0 += 2) {
        const int nv = (j0 < 4) ? 2 : 1;
        bool val[2] = {false, false};
#pragma unroll
        for (int t = 0; t < 2; t++) {
            if (t < nv && (qb - 4 + j0 + t) >= 0) {
                val[t] = true;
                stage64x64 (S + sbase + ((size_t)(j0 + t) << 12), 64, Ss[t], lane, wave);
                stage128x64(Vt + vbase + (size_t)(qb - 4 + j0 + t) * 64, 2048, Vs[t], lane, wave);
            }
        }
        __syncthreads();
#pragma unroll
        for (int t = 0; t < 2; t++) {
            if (!val[t]) continue;
#pragma unroll
            for (int s = 0; s < 2; s++) {
                bf16x8 a[2], bbf[4];
#pragma unroll
                for (int mi = 0; mi < 2; mi++) {
                    const int row = wr * 32 + mi * 16 + n15;
                    a[mi] = *(const bf16x8*)&Ss[t][row * 64 + (((s * 4 + q) ^ (row & 7)) * 8)];
                }
#pragma unroll
                for (int ni = 0; ni < 4; ni++) {
                    const int row = wc * 64 + ni * 16 + n15;
                    bbf[ni] = *(const bf16x8*)&Vs[t][row * 64 + (((s * 4 + q) ^ (row & 7)) * 8)];
                }
#pragma unroll
                for (int mi = 0; mi < 2; mi++)
#pragma unroll
                    for (int ni = 0; ni < 4; ni++)
                        acc[mi][ni] = __builtin_amdgcn_mfma_f32_16x16x32_bf16(a[mi], bbf[ni], acc[mi][ni], 0, 0, 0);
            }
        }
        __syncthreads();
    }

#pragma unroll
    for (int mi = 0; mi < 2; mi++)
#pragma unroll
        for (int ni = 0; ni < 4; ni++)
#pragma unroll
            for (int r = 0; r < 4; r++) {
                const int il = wr * 32 + mi * 16 + q * 4 + r;
                const int cl = wc * 64 + ni * 16 + n15;
                out[((size_t)(b * T_SEQ + qb * 64 + il)) * N_EMBD + c0 + cl] = acc[mi][ni][r];
            }
}

// ---------------------------------------------------------------------------
// K4: in-place LayerNorm over last dim (1024), one WG per row
__global__ __launch_bounds__(256) void k_ln(float* __restrict__ out,
                                            const float* __restrict__ w,
                                            const float* __restrict__ bias) {
    __shared__ float red[8];
    const int t = threadIdx.x;
    float* p = out + (size_t)blockIdx.x * N_EMBD;
    float4 v = ((const float4*)p)[t];
    float s  = v.x + v.y + v.z + v.w;
    float sq = v.x * v.x + v.y * v.y + v.z * v.z + v.w * v.w;
#pragma unroll
    for (int off = 32; off; off >>= 1) {
        s  += __shfl_down(s, off, 64);
        sq += __shfl_down(sq, off, 64);
    }
    const int wave = t >> 6, lane = t & 63;
    if (lane == 0) { red[wave] = s; red[4 + wave] = sq; }
    __syncthreads();
    const float ts = red[0] + red[1] + red[2] + red[3];
    const float tq = red[4] + red[5] + red[6] + red[7];
    const float mean = ts * (1.0f / N_EMBD);
    const float var  = tq * (1.0f / N_EMBD) - mean * mean;
    const float rs = rsqrtf(var + 1e-5f);
    float4 wv = ((const float4*)w)[t];
    float4 bv = ((const float4*)bias)[t];
    float4 o;
    o.x = (v.x - mean) * rs * wv.x + bv.x;
    o.y = (v.y - mean) * rs * wv.y + bv.y;
    o.z = (v.z - mean) * rs * wv.z + bv.z;
    o.w = (v.w - mean) * rs * wv.w + bv.w;
    ((float4*)p)[t] = o;
}

// ---------------------------------------------------------------------------
extern "C" void kernel_launch(void* const* d_in, const int* in_sizes, int n_in,
                              void* d_out, int out_size, void* d_ws, size_t ws_size,
                              hipStream_t stream) {
    const float* x  = (const float*)d_in[0];
    const float* W  = (const float*)d_in[1];
    const float* bq = (const float*)d_in[2];
    const float* lw = (const float*)d_in[3];
    const float* lb = (const float*)d_in[4];
    float* out = (float*)d_out;
    char* ws = (char*)d_ws;

    // workspace layout (bytes):
    //  Xb   @ 0          16,777,216  (8192x1024 bf16) — dead after GEMM
    //  Sbuf @ 0           5,242,880  (4*32*5 blocks of 64x64 bf16) — aliases Xb
    //  WbT  @ 16,777,216  6,291,456  (3072x1024 bf16)
    //  QK   @ 23,068,672 33,554,432  (8192x2048 bf16)
    //  Vt   @ 56,623,104 16,777,216  (4x1024x2048 bf16)
    //  total 73,400,320
    unsigned short* Xb   = (unsigned short*)(ws + 0);
    unsigned short* Sbuf = (unsigned short*)(ws + 0);
    unsigned short* WbT  = (unsigned short*)(ws + 16777216);
    unsigned short* QK   = (unsigned short*)(ws + 23068672);
    unsigned short* Vt   = (unsigned short*)(ws + 56623104);

    k_prep   <<<11264, 256, 0, stream>>>(x, Xb, W, WbT);
    k_gemm   <<<1536,  256, 0, stream>>>(Xb, WbT, bq, QK, Vt);
    k_scores <<<640,   256, 0, stream>>>(QK, Sbuf);
    k_sv     <<<1024,  256, 0, stream>>>(Sbuf, Vt, out);
    k_ln     <<<8192,  256, 0, stream>>>(out, lw, lb);
}